// Round 5
// baseline (141.606 us; speedup 1.0000x reference)
//
#include <hip/hip_runtime.h>

#define T_LEN 2048

typedef float f4 __attribute__((ext_vector_type(4)));
typedef unsigned int u32x2 __attribute__((ext_vector_type(2)));

// --- one timestep, k-split by 8 across the two 32-lane halves ---------------
// Batch occupies 32 lanes (rows {0,2} or {1,3}). Half hi=(lane>=32) covers
// k-offsets {8..} via hs = hi ? ror8(h) : h; each half accumulates 8 rotation
// terms. ONLY the lo half contributes xs*wih + bias (the combine sums both
// halves -- R3/R4 double-counted this term; that was the absmax 1.28 bug).
// Combine is role-independent: r = permlane32_swap(a0, a0); total = r0 + r1
// gives own+partner in every lane under either half-role convention.
__device__ __forceinline__ float stepk(float h, float xs, const float (&w)[8],
                                       float wih_e, float bias_e, bool hi) {
  // hs = hi ? ror8(h) : h  (ror8 is direction-symmetric mod 16).
  int h8 = __builtin_amdgcn_update_dpp(0, __float_as_int(h), 0x128, 0xF, 0xF, true);
  float hs = hi ? __int_as_float(h8) : h;

  // R2-proven fused DPP-fmac core; wih_e/bias_e are 0 on the hi half.
  float a0, a1;
  asm("v_fma_f32      %0, %[xs], %[wih], %[bs]\n\t"
      "v_fmac_f32     %0, %[hs], %[w0]\n\t"
      "v_mul_f32_dpp  %1, %[hs], %[w1] row_ror:1 row_mask:0xf bank_mask:0xf\n\t"
      "v_fmac_f32_dpp %0, %[hs], %[w2] row_ror:2 row_mask:0xf bank_mask:0xf\n\t"
      "v_fmac_f32_dpp %1, %[hs], %[w3] row_ror:3 row_mask:0xf bank_mask:0xf\n\t"
      "v_fmac_f32_dpp %0, %[hs], %[w4] row_ror:4 row_mask:0xf bank_mask:0xf\n\t"
      "v_fmac_f32_dpp %1, %[hs], %[w5] row_ror:5 row_mask:0xf bank_mask:0xf\n\t"
      "v_fmac_f32_dpp %0, %[hs], %[w6] row_ror:6 row_mask:0xf bank_mask:0xf\n\t"
      "v_fmac_f32_dpp %1, %[hs], %[w7] row_ror:7 row_mask:0xf bank_mask:0xf\n\t"
      "v_add_f32      %0, %0, %1"
      : "=&v"(a0), "=&v"(a1)
      : [xs]"v"(xs), [wih]"v"(wih_e), [bs]"v"(bias_e), [hs]"v"(hs),
        [w0]"v"(w[0]), [w1]"v"(w[1]), [w2]"v"(w[2]), [w3]"v"(w[3]),
        [w4]"v"(w[4]), [w5]"v"(w[5]), [w6]"v"(w[6]), [w7]"v"(w[7]));

  // Combine partner k-halves across the 32-lane boundary (VALU, no LDS).
  u32x2 r = __builtin_amdgcn_permlane32_swap(__float_as_uint(a0),
                                             __float_as_uint(a0), false, false);
  return fmaxf(__uint_as_float(r[0]) + __uint_as_float(r[1]), 0.0f);
}

// --- kernel -----------------------------------------------------------------
__global__ __launch_bounds__(256) void rnn_relu_kernel(
    const float* __restrict__ x, const float* __restrict__ W_ih,
    const float* __restrict__ b_ih, const float* __restrict__ W_hh,
    const float* __restrict__ b_hh, const float* __restrict__ W_fc,
    const float* __restrict__ b_fc, float* __restrict__ out) {
  const int tid  = threadIdx.x;
  const int gtid = blockIdx.x * 256 + tid;
  const int j    = tid & 15;              // output index owned by this lane
  const bool hi  = (tid & 32) != 0;       // which k-half this 32-half covers
  // Wave covers 2 batches: rows {0,2} -> batch_sel 0, rows {1,3} -> batch_sel 1.
  const int b    = (gtid >> 6) * 2 + ((tid >> 4) & 1);

  // Probe row_ror:1 direction (ctrl 0x121 == asm row_ror:1), R1/R2-proven.
  int pr = __builtin_amdgcn_update_dpp(0, j, 0x121, 0xF, 0xF, true);
  const bool plus = (pr == ((j + 1) & 15));

  // w[s] = W_hh[j][ (j + dir*s + 8*hi) & 15 ],  s = 0..7
  float w[8];
#pragma unroll
  for (int s = 0; s < 8; ++s) {
    int k = (j + (plus ? s : (16 - s) & 15) + (hi ? 8 : 0)) & 15;
    w[s] = W_hh[j * 16 + k];
  }
  // x/bias contribution only on the lo half (combine would double it).
  const float wih_e  = hi ? 0.0f : W_ih[j];
  const float bias_e = hi ? 0.0f : (b_ih[j] + b_hh[j]);

  // All 32 lanes of a batch load the same x addresses (L1 broadcast).
  const f4* __restrict__ xr = (const f4*)(x + (size_t)b * T_LEN);

  float h = 0.0f;
  f4 c0 = xr[0], c1 = xr[1], c2 = xr[2], c3 = xr[3];

#pragma unroll 1
  for (int t0 = 0; t0 < T_LEN; t0 += 16) {
    // Unconditional prefetch (wraps to chunk 0 on the final iteration).
    const int tn = (t0 + 16) & (T_LEN - 1);
    const f4* p = xr + (tn >> 2);
    f4 n0 = p[0], n1 = p[1], n2 = p[2], n3 = p[3];
    h = stepk(h, c0.x, w, wih_e, bias_e, hi);
    h = stepk(h, c0.y, w, wih_e, bias_e, hi);
    h = stepk(h, c0.z, w, wih_e, bias_e, hi);
    h = stepk(h, c0.w, w, wih_e, bias_e, hi);
    h = stepk(h, c1.x, w, wih_e, bias_e, hi);
    h = stepk(h, c1.y, w, wih_e, bias_e, hi);
    h = stepk(h, c1.z, w, wih_e, bias_e, hi);
    h = stepk(h, c1.w, w, wih_e, bias_e, hi);
    h = stepk(h, c2.x, w, wih_e, bias_e, hi);
    h = stepk(h, c2.y, w, wih_e, bias_e, hi);
    h = stepk(h, c2.z, w, wih_e, bias_e, hi);
    h = stepk(h, c2.w, w, wih_e, bias_e, hi);
    h = stepk(h, c3.x, w, wih_e, bias_e, hi);
    h = stepk(h, c3.y, w, wih_e, bias_e, hi);
    h = stepk(h, c3.z, w, wih_e, bias_e, hi);
    h = stepk(h, c3.w, w, wih_e, bias_e, hi);
    c0 = n0; c1 = n1; c2 = n2; c3 = n3;
  }

  // Epilogue: out[b, c] = sum_j h[j] * W_fc[c, j] + b_fc[c].
  // h replicated across the batch's two 16-rows; butterfly (xor 1,2,4,8) stays
  // within each 16-row; lanes 0 (batch_sel 0) and 16 (batch_sel 1) write.
  float p0 = h * W_fc[j];
  float p1 = h * W_fc[16 + j];
  p0 += __int_as_float(__builtin_amdgcn_ds_swizzle(__float_as_int(p0), 0x041F));
  p1 += __int_as_float(__builtin_amdgcn_ds_swizzle(__float_as_int(p1), 0x041F));
  p0 += __int_as_float(__builtin_amdgcn_ds_swizzle(__float_as_int(p0), 0x081F));
  p1 += __int_as_float(__builtin_amdgcn_ds_swizzle(__float_as_int(p1), 0x081F));
  p0 += __int_as_float(__builtin_amdgcn_ds_swizzle(__float_as_int(p0), 0x101F));
  p1 += __int_as_float(__builtin_amdgcn_ds_swizzle(__float_as_int(p1), 0x101F));
  p0 += __int_as_float(__builtin_amdgcn_ds_swizzle(__float_as_int(p0), 0x201F));
  p1 += __int_as_float(__builtin_amdgcn_ds_swizzle(__float_as_int(p1), 0x201F));

  if ((tid & 47) == 0) {   // lanes 0 (batch_sel 0) and 16 (batch_sel 1)
    out[b * 2 + 0] = p0 + b_fc[0];
    out[b * 2 + 1] = p1 + b_fc[1];
  }
}

// --- launch -----------------------------------------------------------------
extern "C" void kernel_launch(void* const* d_in, const int* in_sizes, int n_in,
                              void* d_out, int out_size, void* d_ws, size_t ws_size,
                              hipStream_t stream) {
  const float* x    = (const float*)d_in[0];
  const float* W_ih = (const float*)d_in[1];
  const float* b_ih = (const float*)d_in[2];
  const float* W_hh = (const float*)d_in[3];
  const float* b_hh = (const float*)d_in[4];
  const float* W_fc = (const float*)d_in[5];
  const float* b_fc = (const float*)d_in[6];
  float* out = (float*)d_out;

  const int B = 4096;
  dim3 grid(B / 8);     // 512 blocks: 2 batches per 64-lane wave
  dim3 block(256);      // 2 blocks/CU -> 8 waves/CU -> 2 waves/SIMD
  hipLaunchKernelGGL(rnn_relu_kernel, grid, block, 0, stream,
                     x, W_ih, b_ih, W_hh, b_hh, W_fc, b_fc, out);
}

// Round 6
// 92.176 us; speedup vs baseline: 1.5363x; 1.5363x over previous
//
#include <hip/hip_runtime.h>

#define T_LEN 2048

typedef float f4 __attribute__((ext_vector_type(4)));

// --- one timestep (R2-proven block, unchanged) -------------------------------
// h_new[j] = relu( x_t*wih[j] + bias[j] + sum_k W_hh[j,k]*h[k] )
// 15 fused DPP rotations (the cross-lane minimum), 4 independent accumulator
// chains. DPP hazard (VALU write -> DPP read needs 2 wait states) satisfied:
// first two instructions don't DPP-read h.
__device__ __forceinline__ void step(float& h, float xs, const float (&w)[16],
                                     float wih, float bias) {
  float a0, a1, a2, a3;
  asm("v_fma_f32 %0, %5, %6, %7\n\t"
      "v_fmac_f32 %0, %4, %8\n\t"
      "v_mul_f32_dpp %1, %4, %9  row_ror:1  row_mask:0xf bank_mask:0xf\n\t"
      "v_mul_f32_dpp %2, %4, %10 row_ror:2  row_mask:0xf bank_mask:0xf\n\t"
      "v_mul_f32_dpp %3, %4, %11 row_ror:3  row_mask:0xf bank_mask:0xf\n\t"
      "v_fmac_f32_dpp %0, %4, %12 row_ror:4  row_mask:0xf bank_mask:0xf\n\t"
      "v_fmac_f32_dpp %1, %4, %13 row_ror:5  row_mask:0xf bank_mask:0xf\n\t"
      "v_fmac_f32_dpp %2, %4, %14 row_ror:6  row_mask:0xf bank_mask:0xf\n\t"
      "v_fmac_f32_dpp %3, %4, %15 row_ror:7  row_mask:0xf bank_mask:0xf\n\t"
      "v_fmac_f32_dpp %0, %4, %16 row_ror:8  row_mask:0xf bank_mask:0xf\n\t"
      "v_fmac_f32_dpp %1, %4, %17 row_ror:9  row_mask:0xf bank_mask:0xf\n\t"
      "v_fmac_f32_dpp %2, %4, %18 row_ror:10 row_mask:0xf bank_mask:0xf\n\t"
      "v_fmac_f32_dpp %3, %4, %19 row_ror:11 row_mask:0xf bank_mask:0xf\n\t"
      "v_fmac_f32_dpp %0, %4, %20 row_ror:12 row_mask:0xf bank_mask:0xf\n\t"
      "v_fmac_f32_dpp %1, %4, %21 row_ror:13 row_mask:0xf bank_mask:0xf\n\t"
      "v_fmac_f32_dpp %2, %4, %22 row_ror:14 row_mask:0xf bank_mask:0xf\n\t"
      "v_fmac_f32_dpp %3, %4, %23 row_ror:15 row_mask:0xf bank_mask:0xf\n\t"
      "v_add_f32 %0, %0, %1\n\t"
      "v_add_f32 %2, %2, %3\n\t"
      "v_add_f32 %0, %0, %2\n\t"
      "v_max_f32 %4, 0, %0"
      : "=&v"(a0), "=&v"(a1), "=&v"(a2), "=&v"(a3), "+v"(h)
      : "v"(xs), "v"(wih), "v"(bias),
        "v"(w[0]), "v"(w[1]), "v"(w[2]), "v"(w[3]),
        "v"(w[4]), "v"(w[5]), "v"(w[6]), "v"(w[7]),
        "v"(w[8]), "v"(w[9]), "v"(w[10]), "v"(w[11]),
        "v"(w[12]), "v"(w[13]), "v"(w[14]), "v"(w[15]));
}

#define STEP16(C0, C1, C2, C3)            \
  do {                                    \
    step(h, (C0).x, w, wih, bias);        \
    step(h, (C0).y, w, wih, bias);        \
    step(h, (C0).z, w, wih, bias);        \
    step(h, (C0).w, w, wih, bias);        \
    step(h, (C1).x, w, wih, bias);        \
    step(h, (C1).y, w, wih, bias);        \
    step(h, (C1).z, w, wih, bias);        \
    step(h, (C1).w, w, wih, bias);        \
    step(h, (C2).x, w, wih, bias);        \
    step(h, (C2).y, w, wih, bias);        \
    step(h, (C2).z, w, wih, bias);        \
    step(h, (C2).w, w, wih, bias);        \
    step(h, (C3).x, w, wih, bias);        \
    step(h, (C3).y, w, wih, bias);        \
    step(h, (C3).z, w, wih, bias);        \
    step(h, (C3).w, w, wih, bias);        \
  } while (0)

// --- kernel -----------------------------------------------------------------
__global__ __launch_bounds__(256) void rnn_relu_kernel(
    const float* __restrict__ x, const float* __restrict__ W_ih,
    const float* __restrict__ b_ih, const float* __restrict__ W_hh,
    const float* __restrict__ b_hh, const float* __restrict__ W_fc,
    const float* __restrict__ b_fc, float* __restrict__ out) {
  const int tid = threadIdx.x;
  const int j   = tid & 15;                        // h index owned by this lane
  const int b   = blockIdx.x * 16 + (tid >> 4);    // batch per 16-lane row

  // Probe row_ror:1 direction (ctrl 0x121 == asm row_ror:1), R1/R2-proven.
  int pr = __builtin_amdgcn_update_dpp(0, j, 0x121, 0xF, 0xF, true);
  const bool plus = (pr == ((j + 1) & 15));

  // w[s] = W_hh[j][sigma_s(j)] so ror_s(h)*w[s] contributes W_hh[j,k]*h[k].
  float w[16];
#pragma unroll
  for (int s = 0; s < 16; ++s) {
    int k = (j + (plus ? s : (16 - s))) & 15;
    w[s] = W_hh[j * 16 + k];
  }
  const float wih  = W_ih[j];
  const float bias = b_ih[j] + b_hh[j];

  // Each lane loads its batch row's x (identical within the 16-lane group ->
  // L1 broadcast). Double-buffered A/B register sets, loads issued a full 16
  // steps (~1000+ cyc) before first use; no register copies, no branch in body.
  const f4* __restrict__ xr = (const f4*)(x + (size_t)b * T_LEN);

  float h = 0.0f;
  f4 A0 = xr[0], A1 = xr[1], A2 = xr[2], A3 = xr[3];
  f4 B0, B1, B2, B3;
  const f4* p = xr + 4;                    // chunk t0+16 (B buffer source)

#pragma unroll 1
  for (int t0 = 0; t0 < T_LEN; t0 += 32) {
    B0 = p[0]; B1 = p[1]; B2 = p[2]; B3 = p[3];     // load chunk t0+16
    STEP16(A0, A1, A2, A3);                          // steps t0 .. t0+15
    const f4* pa = (t0 + 32 < T_LEN) ? (p + 4) : xr; // wrap on final iter
    A0 = pa[0]; A1 = pa[1]; A2 = pa[2]; A3 = pa[3];  // load chunk t0+32
    STEP16(B0, B1, B2, B3);                          // steps t0+16 .. t0+31
    p += 8;
  }

  // Epilogue: out[b, c] = sum_j h[j] * W_fc[c, j] + b_fc[c]  (R2-proven)
  float p0 = h * W_fc[j];
  float p1 = h * W_fc[16 + j];
  p0 += __int_as_float(__builtin_amdgcn_ds_swizzle(__float_as_int(p0), 0x041F));
  p1 += __int_as_float(__builtin_amdgcn_ds_swizzle(__float_as_int(p1), 0x041F));
  p0 += __int_as_float(__builtin_amdgcn_ds_swizzle(__float_as_int(p0), 0x081F));
  p1 += __int_as_float(__builtin_amdgcn_ds_swizzle(__float_as_int(p1), 0x081F));
  p0 += __int_as_float(__builtin_amdgcn_ds_swizzle(__float_as_int(p0), 0x101F));
  p1 += __int_as_float(__builtin_amdgcn_ds_swizzle(__float_as_int(p1), 0x101F));
  p0 += __int_as_float(__builtin_amdgcn_ds_swizzle(__float_as_int(p0), 0x201F));
  p1 += __int_as_float(__builtin_amdgcn_ds_swizzle(__float_as_int(p1), 0x201F));

  if (j == 0) {
    out[b * 2 + 0] = p0 + b_fc[0];
    out[b * 2 + 1] = p1 + b_fc[1];
  }
}

// --- launch -----------------------------------------------------------------
extern "C" void kernel_launch(void* const* d_in, const int* in_sizes, int n_in,
                              void* d_out, int out_size, void* d_ws, size_t ws_size,
                              hipStream_t stream) {
  const float* x    = (const float*)d_in[0];
  const float* W_ih = (const float*)d_in[1];
  const float* b_ih = (const float*)d_in[2];
  const float* W_hh = (const float*)d_in[3];
  const float* b_hh = (const float*)d_in[4];
  const float* W_fc = (const float*)d_in[5];
  const float* b_fc = (const float*)d_in[6];
  float* out = (float*)d_out;

  const int B = 4096;
  dim3 grid(B / 16);   // 256 blocks: 4 batches per wave, 1024 waves = 1/SIMD
  dim3 block(256);
  hipLaunchKernelGGL(rnn_relu_kernel, grid, block, 0, stream,
                     x, W_ih, b_ih, W_hh, b_hh, W_fc, b_fc, out);
}